// Round 10
// baseline (243.636 us; speedup 1.0000x reference)
//
#include <hip/hip_runtime.h>
#include <cstdint>

typedef unsigned short u16;
typedef __bf16 bf16;
typedef bf16 bf16x8 __attribute__((ext_vector_type(8)));
typedef u16 u16x4 __attribute__((ext_vector_type(4)));
typedef u16 u16x8 __attribute__((ext_vector_type(8)));
typedef float f32x4 __attribute__((ext_vector_type(4)));

__device__ __forceinline__ u16 f2b(float f) {
    return __builtin_bit_cast(u16, (bf16)f);
}
__device__ __forceinline__ float b2f(u16 u) {
    return __uint_as_float(((unsigned)u) << 16);
}
__device__ __forceinline__ float ex2(float x) {
#if __has_builtin(__builtin_amdgcn_exp2f)
    return __builtin_amdgcn_exp2f(x);   // v_exp_f32: 2^x
#else
    return exp2f(x);
#endif
}
__device__ __forceinline__ void load_lds16(const void* g, void* l) {
    auto gp = reinterpret_cast<const __attribute__((address_space(1))) void*>(
        reinterpret_cast<uintptr_t>(g));
    auto lp = reinterpret_cast<__attribute__((address_space(3))) void*>(
        reinterpret_cast<uintptr_t>(l));
    __builtin_amdgcn_global_load_lds(gp, lp, 16, 0, 0);
}
__device__ __forceinline__ f32x4 mfma16(bf16x8 a, bf16x8 b, f32x4 c) {
    return __builtin_amdgcn_mfma_f32_16x16x32_bf16(a, b, c, 0, 0, 0);
}

#define LOG2E 1.44269504088896340736f

// ---------------------------------------------------------------- prep: x->bf16 + both weight transposes
__global__ __launch_bounds__(256) void prep_kernel(const float* __restrict__ x,
                                                   u16* __restrict__ xb,
                                                   const float* __restrict__ wa,
                                                   const float* __restrict__ wp,
                                                   u16* __restrict__ wTa,
                                                   u16* __restrict__ wTp) {
    __shared__ float tile[32][33];
    const int bx = blockIdx.x;
    if (bx < 2048) {
        const int n4 = 8192 * 768 / 4;
        int i = bx * 256 + threadIdx.x;
        for (; i < n4; i += 2048 * 256) {
            float4 v = ((const float4*)x)[i];
            u16x4 r;
            r[0] = f2b(v.x); r[1] = f2b(v.y); r[2] = f2b(v.z); r[3] = f2b(v.w);
            *(u16x4*)&xb[(size_t)i * 4] = r;
        }
        return;
    }
    const int idx = bx - 2048;          // [0, 2304): 96 n-tiles x 24 k-tiles
    const int nx = idx % 96, ky = idx / 96;
    const float* w;
    u16* wT;
    int N, n0;
    if (nx < 72) { w = wa; wT = wTa; N = 2304; n0 = nx * 32; }
    else         { w = wp; wT = wTp; N = 768;  n0 = (nx - 72) * 32; }
    const int K = 768, k0 = ky * 32;
    const int tx = threadIdx.x & 31, ty = threadIdx.x >> 5;
#pragma unroll
    for (int i = 0; i < 4; ++i)
        tile[ty + i * 8][tx] = w[(size_t)(k0 + ty + i * 8) * N + n0 + tx];
    __syncthreads();
#pragma unroll
    for (int i = 0; i < 4; ++i)
        wT[(size_t)(n0 + ty + i * 8) * K + k0 + tx] = f2b(tile[tx][ty + i * 8]);
}

// ---------------------------------------------------------------- GEMM: C[M][N] = A[M][K] * Bt[N][K]^T + bias
// MODE 0: plain f32 output (proj GEMM).
// MODE 1: qkv GEMM -- bf16 output; Q columns (col<768) pre-scaled by log2e;
//         V-region blocks (tn>=1536) write TRANSPOSED into vt[bh][d][s] and
//         reduce per-64-row column sums into ts_raw[bh][st][d] (no qkv write).
// 128x128 tile, 4 waves, 16x16x32 MFMA, dbuf gload_lds staging, swapped-operand
// epilogue (lane holds 4 consecutive C-columns), XCD-aware block swizzle.
template <int MODE>
__global__ __launch_bounds__(256, 2) void gemm_kernel(const u16* __restrict__ A,
                                                      const u16* __restrict__ Bt,
                                                      const float* __restrict__ bias,
                                                      void* __restrict__ out,
                                                      u16* __restrict__ vt,
                                                      float* __restrict__ ts_raw,
                                                      int M, int N, int K) {
    __shared__ __align__(16) u16 SMEM[4 * 128 * 64];   // A0,B0,A1,B1 (64 KB)
    const int tid = threadIdx.x;
    const int wave = tid >> 6, lane = tid & 63;
    const int l15 = lane & 15, lg = lane >> 4;
    const int gx = gridDim.x;
    const int nwg = gx * gridDim.y;
    const int lin = blockIdx.y * gx + blockIdx.x;
    const int swz = (lin & 7) * (nwg >> 3) + (lin >> 3);
    const int tm = (swz / gx) * 128, tn = (swz % gx) * 128;
    const int wr = (wave >> 1) * 64, wc = (wave & 1) * 64;

    f32x4 acc[4][4] = {};

    const int rbase = wave * 8 + (lane >> 3);
    const int sslot = (lane & 7) ^ (rbase & 7);
    const u16* gA = A + (size_t)(tm + rbase) * K + sslot * 8;
    const u16* gB = Bt + (size_t)(tn + rbase) * K + sslot * 8;
    const int woff = wave * 8 * 64;
    const int nkt = K >> 6;

#pragma unroll
    for (int i = 0; i < 4; ++i) {
        load_lds16(gA + (size_t)i * 32 * K, SMEM + woff + i * 32 * 64);
        load_lds16(gB + (size_t)i * 32 * K, SMEM + 8192 + woff + i * 32 * 64);
    }

    for (int kt = 0; kt < nkt; ++kt) {
        __syncthreads();  // buf[cur] ready (loads issued one iter ago); prev reads done
        const int cur = kt & 1;
        if (kt + 1 < nkt) {
            u16* ldsA = SMEM + (cur ^ 1) * 2 * 8192 + woff;
            u16* ldsB = ldsA + 8192;
#pragma unroll
            for (int i = 0; i < 4; ++i) {
                load_lds16(gA + (size_t)i * 32 * K + (kt + 1) * 64, ldsA + i * 32 * 64);
                load_lds16(gB + (size_t)i * 32 * K + (kt + 1) * 64, ldsB + i * 32 * 64);
            }
        }
        const u16* As = SMEM + cur * 2 * 8192;
        const u16* Bs = As + 8192;
#pragma unroll
        for (int kk = 0; kk < 64; kk += 32) {
            const int sb = kk >> 3;
            bf16x8 af[4], bfr[4];
#pragma unroll
            for (int m = 0; m < 4; ++m) {
                int row = wr + m * 16 + l15;
                af[m] = *(const bf16x8*)&As[row * 64 + (((sb + lg) ^ (row & 7))) * 8];
            }
#pragma unroll
            for (int n = 0; n < 4; ++n) {
                int row = wc + n * 16 + l15;
                bfr[n] = *(const bf16x8*)&Bs[row * 64 + (((sb + lg) ^ (row & 7))) * 8];
            }
#pragma unroll
            for (int m = 0; m < 4; ++m)
#pragma unroll
                for (int n = 0; n < 4; ++n)
                    acc[m][n] = mfma16(bfr[n], af[m], acc[m][n]);  // swapped: cols on regs
        }
    }

    if (MODE == 1 && tn >= 1536) {
        // V-region block: transposed store into vt + per-64-s-tile column sums.
        const int b = tm >> 11;
        const int s0 = (tm & 2047) + wr;          // wave's first s (64-aligned)
        const int st = s0 >> 6;
        const int hh = (tn + wc - 1536) >> 6;     // head index of this wave's 64 cols
        const int bh = b * 12 + hh;
        f32x4 colsum[4] = {};
#pragma unroll
        for (int m = 0; m < 4; ++m) {
            const int s = s0 + m * 16 + l15;
#pragma unroll
            for (int n = 0; n < 4; ++n) {
                const int col = tn + wc + n * 16 + lg * 4;
                f32x4 v = acc[m][n] + *(const f32x4*)&bias[col];
                colsum[n] += v;
                const int dl = n * 16 + lg * 4;
#pragma unroll
                for (int r = 0; r < 4; ++r)
                    vt[((size_t)bh * 64 + dl + r) * 2048 + s] = f2b(v[r]);
            }
        }
#pragma unroll
        for (int n = 0; n < 4; ++n)
#pragma unroll
            for (int off = 1; off < 16; off <<= 1) {
                colsum[n][0] += __shfl_xor(colsum[n][0], off);
                colsum[n][1] += __shfl_xor(colsum[n][1], off);
                colsum[n][2] += __shfl_xor(colsum[n][2], off);
                colsum[n][3] += __shfl_xor(colsum[n][3], off);
            }
        if (l15 == 0) {
#pragma unroll
            for (int n = 0; n < 4; ++n)
                *(f32x4*)&ts_raw[((size_t)bh * 32 + st) * 64 + n * 16 + lg * 4] =
                    colsum[n];
        }
        return;
    }

    const float sc = (MODE == 1 && tn < 768) ? LOG2E : 1.f;   // pre-scale Q by log2e
#pragma unroll
    for (int m = 0; m < 4; ++m) {
        const size_t row = (size_t)(tm + wr + m * 16 + l15);
#pragma unroll
        for (int n = 0; n < 4; ++n) {
            const int col = tn + wc + n * 16 + lg * 4;
            f32x4 v = (acc[m][n] + *(const f32x4*)&bias[col]) * sc;
            if constexpr (MODE == 1) {
                u16x4 pk;
#pragma unroll
                for (int r = 0; r < 4; ++r) pk[r] = f2b(v[r]);
                *(u16x4*)&((u16*)out)[row * N + col] = pk;
            } else {
                *(f32x4*)&((float*)out)[row * N + col] = v;
            }
        }
    }
}

// ---------------------------------------------------------------- attention
// Swapped-operand flash, QBLK=128 (4 waves x 32 q-rows, two q-fragments each),
// KBLK=64, defer-max in exp2 domain (Q pre-scaled by log2e in gemm1), K-row
// permutation so softmax'd P is ALREADY in PV's B-fragment layout (no P LDS
// round-trip). K/V fragments are loaded ONCE per tile and shared by both
// q-halves (halves ds_read traffic); tile count / barriers / votes halve vs
// QBLK=64. LDS stays 32 KB (K/V dbuf only). Unroll-by-2 main loop: static
// buffer indices; staging dests are per-wave chunks, MFMA reads use BUFFER BASE.
__global__ __launch_bounds__(256, 4) void attn_kernel(const u16* __restrict__ qkv,
                                                      const u16* __restrict__ vt,
                                                      const float* __restrict__ ts_raw,
                                                      u16* __restrict__ aout) {
    __shared__ __align__(16) u16 Ks[2][64 * 64];
    __shared__ __align__(16) u16 Vs[2][64 * 64];   // transposed V: [d][k]
    const int bh = blockIdx.x;                     // bh fastest: same-bh blocks share XCD L2
    const int qt = 15 - blockIdx.y;                // longest-first dispatch
    const int b = bh / 12, h = bh % 12;
    const int tid = threadIdx.x, wave = tid >> 6, lane = tid & 63;
    const int l15 = lane & 15, lg = lane >> 4;
    const int q0 = qt * 128 + wave * 32;
    const size_t rowbase = (size_t)b * 2048;
    const float MASKVAL = 1e-9f * LOG2E;           // reference's 1e-9, log2 domain
    const float THR2 = 8.0f * LOG2E;               // defer-max threshold (8 nats)

    bf16x8 qf[2][2];          // [m][ks]: Q[q0+m*16+l15][ks*32+lg*8 ..]
#pragma unroll
    for (int m = 0; m < 2; ++m)
#pragma unroll
        for (int ks = 0; ks < 2; ++ks)
            qf[m][ks] = *(const bf16x8*)(qkv + (rowbase + q0 + m * 16 + l15) * 2304 +
                                         h * 64 + ks * 32 + lg * 8);

    f32x4 o[2][4] = {};       // O^T: lane holds O[q0+m*16+l15][d = dn*16 + lg*4 + r]
    float mrun = -1e30f;      // running max (wave-uniform after first rescale), log2 domain
    f32x4 lacc[2] = {};       // per-lane partial l per q-half

    const int rbase = wave * 8 + (lane >> 3);
    const int sslot = (lane & 7) ^ (rbase & 7);
    const int sig0 = ((rbase & 0x1C) << 1) | (rbase & 3);   // K-row permutation base
    const u16* gK = qkv + (rowbase + sig0) * 2304 + 768 + h * 64 + sslot * 8;
    const u16* gV = vt + ((size_t)bh * 64 + rbase) * 2048 + sslot * 8;
    const int ldsoff = wave * 8 * 64;
    // staging destinations (per-wave chunk within each buffer)
    u16* sK0 = &Ks[0][ldsoff];
    u16* sK1 = &Ks[1][ldsoff];
    u16* sV0 = &Vs[0][ldsoff];
    u16* sV1 = &Vs[1][ldsoff];
    // loop-invariant swizzled slot offsets (row&7 == l15&7 for all fragment rows)
    const int xk0 = ((0 + lg) ^ (l15 & 7)) * 8;
    const int xk1 = ((4 + lg) ^ (l15 & 7)) * 8;

#define STAGE_PAIR(Kd, Vd, kp, vp)                       \
    load_lds16(kp, Kd);                                  \
    load_lds16(kp + (size_t)4 * 2304, Kd + 32 * 64);     \
    load_lds16(vp, Vd);                                  \
    load_lds16(vp + (size_t)32 * 2048, Vd + 32 * 64);

    auto process = [&](const u16* Kb, const u16* Vb, int kt) {   // Kb/Vb = BUFFER BASE
        f32x4 s0[4] = {}, s1[4] = {};
        __builtin_amdgcn_s_setprio(1);
#pragma unroll
        for (int n = 0; n < 4; ++n) {
            const int ra = (n * 16 + l15) * 64;
            bf16x8 a0 = *(const bf16x8*)&Kb[ra + xk0];
            bf16x8 a1 = *(const bf16x8*)&Kb[ra + xk1];
            s0[n] = mfma16(a0, qf[0][0], s0[n]);
            s1[n] = mfma16(a0, qf[1][0], s1[n]);
            s0[n] = mfma16(a1, qf[0][1], s0[n]);
            s1[n] = mfma16(a1, qf[1][1], s1[n]);
        }
        __builtin_amdgcn_s_setprio(0);

        if (kt >= 2 * qt) {                   // diagonal-region tiles (true k via sigma)
            const int kb = kt * 64 + lg * 8;
#pragma unroll
            for (int n = 0; n < 4; ++n) {
                const int kn = kb + (n & 1) * 32 + ((n >> 1) << 2);
#pragma unroll
                for (int r = 0; r < 4; ++r) {
                    if (kn + r > q0 + l15)      s0[n][r] = MASKVAL;
                    if (kn + r > q0 + 16 + l15) s1[n][r] = MASKVAL;
                }
            }
        }

        // defer-max: lane-local max over both q-halves; rescale only when >THR
        float mx = fmaxf(fmaxf(s0[0][0], s0[0][1]), fmaxf(s0[0][2], s0[0][3]));
#pragma unroll
        for (int n = 1; n < 4; ++n)
            mx = fmaxf(mx, fmaxf(fmaxf(s0[n][0], s0[n][1]),
                                 fmaxf(s0[n][2], s0[n][3])));
#pragma unroll
        for (int n = 0; n < 4; ++n)
            mx = fmaxf(mx, fmaxf(fmaxf(s1[n][0], s1[n][1]),
                                 fmaxf(s1[n][2], s1[n][3])));
        if (__any(mx > mrun + THR2)) {
            float rm = fmaxf(mx, __shfl_xor(mx, 16));
            rm = fmaxf(rm, __shfl_xor(rm, 32));
            const float mnew = fmaxf(mrun, rm);
            const float alpha = ex2(mrun - mnew);
            mrun = mnew;
            lacc[0] *= alpha;
            lacc[1] *= alpha;
#pragma unroll
            for (int m = 0; m < 2; ++m)
#pragma unroll
                for (int dn = 0; dn < 4; ++dn) o[m][dn] *= alpha;
        }

#pragma unroll
        for (int n = 0; n < 4; ++n)
#pragma unroll
            for (int r = 0; r < 4; ++r) {
                s0[n][r] = ex2(s0[n][r] - mrun);   // bounded by 2^11.5
                s1[n][r] = ex2(s1[n][r] - mrun);
            }
        lacc[0] += (s0[0] + s0[1]) + (s0[2] + s0[3]);
        lacc[1] += (s1[0] + s1[1]) + (s1[2] + s1[3]);

        bf16x8 bp00, bp01, bp10, bp11;        // [m][ks] PV B-fragments (register relabel)
#pragma unroll
        for (int j = 0; j < 4; ++j) {
            bp00[j]     = (bf16)s0[0][j];
            bp00[j + 4] = (bf16)s0[2][j];
            bp01[j]     = (bf16)s0[1][j];
            bp01[j + 4] = (bf16)s0[3][j];
            bp10[j]     = (bf16)s1[0][j];
            bp10[j + 4] = (bf16)s1[2][j];
            bp11[j]     = (bf16)s1[1][j];
            bp11[j + 4] = (bf16)s1[3][j];
        }

        __builtin_amdgcn_s_setprio(1);
#pragma unroll
        for (int dn = 0; dn < 4; ++dn) {
            const int ra = (dn * 16 + l15) * 64;
            bf16x8 v0 = *(const bf16x8*)&Vb[ra + xk0];
            bf16x8 v1 = *(const bf16x8*)&Vb[ra + xk1];
            o[0][dn] = mfma16(v0, bp00, o[0][dn]);
            o[1][dn] = mfma16(v0, bp10, o[1][dn]);
            o[0][dn] = mfma16(v1, bp01, o[0][dn]);
            o[1][dn] = mfma16(v1, bp11, o[1][dn]);
        }
        __builtin_amdgcn_s_setprio(0);
    };

    const int nkt = 2 * qt + 2;               // always even
    STAGE_PAIR(sK0, sV0, gK, gV);             // prologue: tile 0 -> buf0
    const u16* gKp = gK + (size_t)64 * 2304;  // next tile to stage
    const u16* gVp = gV + 64;

    int kt = 0;
    for (;;) {
        __syncthreads();
        if (kt + 1 < nkt) {
            STAGE_PAIR(sK1, sV1, gKp, gVp);
            gKp += (size_t)64 * 2304; gVp += 64;
        }
        process(Ks[0], Vs[0], kt);
        if (++kt == nkt) break;
        __syncthreads();
        if (kt + 1 < nkt) {
            STAGE_PAIR(sK0, sV0, gKp, gVp);
            gKp += (size_t)64 * 2304; gVp += 64;
        }
        process(Ks[1], Vs[1], kt);
        if (++kt == nkt) break;
    }
#undef STAGE_PAIR

    // fold per-lane l across the 4 lane-groups of each row (once, not per tile)
    float lrun[2];
#pragma unroll
    for (int m = 0; m < 2; ++m) {
        float lr = (lacc[m][0] + lacc[m][1]) + (lacc[m][2] + lacc[m][3]);
        lr += __shfl_xor(lr, 16);
        lr += __shfl_xor(lr, 32);
        lrun[m] = lr;
    }

    // analytic future tail: all k >= (qt+1)*128 carry score exactly 1e-9
    if (qt < 15) {
        const float nf = (float)((15 - qt) * 128);
        const float mnew = fmaxf(mrun, MASKVAL);
        const float a = ex2(mrun - mnew);
        const float c = ex2(MASKVAL - mnew);
        lrun[0] = lrun[0] * a + nf * c;
        lrun[1] = lrun[1] * a + nf * c;
        f32x4 suf[4] = {};
        for (int t = 2 * qt + 2; t < 32; ++t) {
            const float* sp = ts_raw + ((size_t)bh * 32 + t) * 64;
#pragma unroll
            for (int dn = 0; dn < 4; ++dn)
                suf[dn] += *(const f32x4*)&sp[dn * 16 + lg * 4];
        }
#pragma unroll
        for (int m = 0; m < 2; ++m)
#pragma unroll
            for (int dn = 0; dn < 4; ++dn)
                o[m][dn] = o[m][dn] * a + suf[dn] * c;
    }

    // normalize + store merged-head layout [B*S][768] bf16
#pragma unroll
    for (int m = 0; m < 2; ++m) {
        const float inv = 1.f / lrun[m];
        const size_t row = rowbase + q0 + m * 16 + l15;
#pragma unroll
        for (int dn = 0; dn < 4; ++dn) {
            u16x4 st;
#pragma unroll
            for (int r = 0; r < 4; ++r) st[r] = f2b(o[m][dn][r] * inv);
            *(u16x4*)&aout[row * 768 + h * 64 + dn * 16 + lg * 4] = st;
        }
    }
}

// ---------------------------------------------------------------- launch
extern "C" void kernel_launch(void* const* d_in, const int* in_sizes, int n_in,
                              void* d_out, int out_size, void* d_ws, size_t ws_size,
                              hipStream_t stream) {
    const float* x      = (const float*)d_in[0];
    const float* w_attn = (const float*)d_in[1];
    const float* b_attn = (const float*)d_in[2];
    const float* w_proj = (const float*)d_in[3];
    const float* b_proj = (const float*)d_in[4];
    float* out = (float*)d_out;
    char* ws = (char*)d_ws;

    u16* xb       = (u16*)(ws + 0);          // 8192*768   bf16 = 12,582,912 B
    u16* wTa      = (u16*)(ws + 12582912);   // 2304*768   bf16 =  3,538,944 B
    u16* wTp      = (u16*)(ws + 16121856);   //  768*768   bf16 =  1,179,648 B
    u16* qkv      = (u16*)(ws + 17301504);   // 8192*2304  bf16 = 37,748,736 B (V third unused)
    u16* vt       = (u16*)(ws + 55050240);   // 48*64*2048 bf16 = 12,582,912 B
    float* ts_raw = (float*)(ws + 67633152); // 48*32*64   f32  =    393,216 B
    u16* aout     = (u16*)(ws + 0);          // aliases xb (dead after gemm1)
    // high-water: 68,026,368 B

    prep_kernel<<<dim3(2048 + 2304), dim3(256), 0, stream>>>(x, xb, w_attn, w_proj,
                                                             wTa, wTp);
    gemm_kernel<1><<<dim3(18, 64), dim3(256), 0, stream>>>(xb, wTa, b_attn,
                                                           (void*)qkv, vt, ts_raw,
                                                           8192, 2304, 768);
    attn_kernel<<<dim3(48, 16), dim3(256), 0, stream>>>(qkv, vt, ts_raw, aout);
    gemm_kernel<0><<<dim3(6, 64), dim3(256), 0, stream>>>(aout, wTp, b_proj,
                                                          (void*)out, nullptr, nullptr,
                                                          8192, 768, 768);
}